// Round 1
// baseline (1048.202 us; speedup 1.0000x reference)
//
#include <hip/hip_runtime.h>

#define HDIM 16
#define TSTEPS 1024
#define NSEQ 4096

// Broadcast lane J (J<16) of each 16-lane subgroup to all lanes of that
// subgroup. ds_swizzle BitMode: offset = (xor<<10)|(or<<5)|and; src_lane =
// ((lane & and) | or) ^ xor, within 32-lane groups. and=0x10 keeps the
// 16-half bit, or=J selects the source lane.
template <int J>
__device__ __forceinline__ float bc16(float v) {
    return __int_as_float(
        __builtin_amdgcn_ds_swizzle(__float_as_int(v), (J << 5) | 0x10));
}

#define BCALL(dst, v)                                                    \
    do {                                                                 \
        dst[0] = bc16<0>(v);   dst[1] = bc16<1>(v);                      \
        dst[2] = bc16<2>(v);   dst[3] = bc16<3>(v);                      \
        dst[4] = bc16<4>(v);   dst[5] = bc16<5>(v);                      \
        dst[6] = bc16<6>(v);   dst[7] = bc16<7>(v);                      \
        dst[8] = bc16<8>(v);   dst[9] = bc16<9>(v);                      \
        dst[10] = bc16<10>(v); dst[11] = bc16<11>(v);                    \
        dst[12] = bc16<12>(v); dst[13] = bc16<13>(v);                    \
        dst[14] = bc16<14>(v); dst[15] = bc16<15>(v);                    \
    } while (0)

__device__ __forceinline__ float sigf(float v) {
    // 1/(1+exp(-v)); v_rcp is ~1ulp, fine vs 6.3e-3 threshold
    return __builtin_amdgcn_rcpf(1.0f + __expf(-v));
}
__device__ __forceinline__ float tanh_fast(float u) {
    // tanh(u) = 1 - 2/(exp(2u)+1); exp overflow -> rcp(inf)=0 -> +1, correct
    return 1.0f - 2.0f * __builtin_amdgcn_rcpf(__expf(2.0f * u) + 1.0f);
}

__global__ __launch_bounds__(256, 1) void gru3_fused(
    const float* __restrict__ x,      // [4096,1024,1]
    const float* __restrict__ w_ih0,  // [48,1]
    const float* __restrict__ w_ih12, // [2,48,16]
    const float* __restrict__ w_hh,   // [3,48,16]
    const float* __restrict__ b_ih,   // [3,48]
    const float* __restrict__ b_hh,   // [3,48]
    const float* __restrict__ fc_w,   // [5,16]
    const float* __restrict__ fc_b,   // [5]
    float* __restrict__ out)          // [4096,5]
{
    const int tid = blockIdx.x * blockDim.x + threadIdx.x;
    const int seq = tid >> 4;
    const int i = tid & 15;  // hidden unit owned by this lane

    // ---- per-lane weights in VGPRs: rows {i, 16+i, 32+i} of each matrix
    float whh[3][3][16];  // [layer][gate r,z,n][j]
    float wih[2][3][16];  // layers 1,2 input-side
#pragma unroll
    for (int l = 0; l < 3; ++l)
#pragma unroll
        for (int g = 0; g < 3; ++g)
#pragma unroll
            for (int j = 0; j < 16; ++j)
                whh[l][g][j] = w_hh[(l * 48 + g * 16 + i) * 16 + j];
#pragma unroll
    for (int l = 0; l < 2; ++l)
#pragma unroll
        for (int g = 0; g < 3; ++g)
#pragma unroll
            for (int j = 0; j < 16; ++j)
                wih[l][g][j] = w_ih12[(l * 48 + g * 16 + i) * 16 + j];

    float br[3], bz[3], bnx[3], bnh[3];
#pragma unroll
    for (int l = 0; l < 3; ++l) {
        br[l]  = b_ih[l * 48 + i]      + b_hh[l * 48 + i];       // r: merge
        bz[l]  = b_ih[l * 48 + 16 + i] + b_hh[l * 48 + 16 + i];  // z: merge
        bnx[l] = b_ih[l * 48 + 32 + i];  // n: b_ih outside r*(...)
        bnh[l] = b_hh[l * 48 + 32 + i];  // n: b_hh inside r*(...)
    }
    const float wxr = w_ih0[i], wxz = w_ih0[16 + i], wxn = w_ih0[32 + i];

    // replicated hidden vectors (each lane holds the full 16-vector)
    float h0b[16], h1b[16], h2b[16];
#pragma unroll
    for (int j = 0; j < 16; ++j) { h0b[j] = 0.f; h1b[j] = 0.f; h2b[j] = 0.f; }
    float h0o = 0.f, h1o = 0.f, h2o = 0.f;  // this lane's own hidden value

    const float* xp = x + seq * TSTEPS;
    float xv = xp[i];  // 16 timesteps staged across the subgroup

    for (int tb = 0; tb < 64; ++tb) {
        const int nxt = (tb < 63) ? (tb + 1) * 16 : 1008;  // clamp (discarded)
        float xvn = xp[nxt + i];  // prefetch next block, hidden by 16 steps
#pragma unroll 2
        for (int k = 0; k < 16; ++k) {
            const float xt = __shfl(xv, k, 16);

            // ---- layer 0 (input dim 1)
            float ar = fmaf(wxr, xt, br[0]);
            float az = fmaf(wxz, xt, bz[0]);
            float anx = fmaf(wxn, xt, bnx[0]);
            float anh = bnh[0];
#pragma unroll
            for (int j = 0; j < 16; ++j) {
                ar  = fmaf(whh[0][0][j], h0b[j], ar);
                az  = fmaf(whh[0][1][j], h0b[j], az);
                anh = fmaf(whh[0][2][j], h0b[j], anh);
            }
            {
                const float r = sigf(ar), z = sigf(az);
                const float n = tanh_fast(fmaf(r, anh, anx));
                h0o = n + z * (h0o - n);
            }
            BCALL(h0b, h0o);  // serves L1-ih now AND L0-hh next step

            // ---- layer 1: hh part first (indep of h0 broadcast)
            float ar1 = br[1], az1 = bz[1], anx1 = bnx[1], anh1 = bnh[1];
#pragma unroll
            for (int j = 0; j < 16; ++j) {
                ar1  = fmaf(whh[1][0][j], h1b[j], ar1);
                az1  = fmaf(whh[1][1][j], h1b[j], az1);
                anh1 = fmaf(whh[1][2][j], h1b[j], anh1);
            }
#pragma unroll
            for (int j = 0; j < 16; ++j) {
                ar1  = fmaf(wih[0][0][j], h0b[j], ar1);
                az1  = fmaf(wih[0][1][j], h0b[j], az1);
                anx1 = fmaf(wih[0][2][j], h0b[j], anx1);
            }
            {
                const float r = sigf(ar1), z = sigf(az1);
                const float n = tanh_fast(fmaf(r, anh1, anx1));
                h1o = n + z * (h1o - n);
            }
            BCALL(h1b, h1o);

            // ---- layer 2
            float ar2 = br[2], az2 = bz[2], anx2 = bnx[2], anh2 = bnh[2];
#pragma unroll
            for (int j = 0; j < 16; ++j) {
                ar2  = fmaf(whh[2][0][j], h2b[j], ar2);
                az2  = fmaf(whh[2][1][j], h2b[j], az2);
                anh2 = fmaf(whh[2][2][j], h2b[j], anh2);
            }
#pragma unroll
            for (int j = 0; j < 16; ++j) {
                ar2  = fmaf(wih[1][0][j], h1b[j], ar2);
                az2  = fmaf(wih[1][1][j], h1b[j], az2);
                anx2 = fmaf(wih[1][2][j], h1b[j], anx2);
            }
            {
                const float r = sigf(ar2), z = sigf(az2);
                const float n = tanh_fast(fmaf(r, anh2, anx2));
                h2o = n + z * (h2o - n);
            }
            BCALL(h2b, h2o);
        }
        xv = xvn;
    }

    // ---- linear head on last timestep: h2b is fully replicated
    if (i < 5) {
        float acc = fc_b[i];
#pragma unroll
        for (int j = 0; j < 16; ++j)
            acc = fmaf(fc_w[i * 16 + j], h2b[j], acc);
        out[seq * 5 + i] = acc;
    }
}

extern "C" void kernel_launch(void* const* d_in, const int* in_sizes, int n_in,
                              void* d_out, int out_size, void* d_ws, size_t ws_size,
                              hipStream_t stream) {
    const float* x      = (const float*)d_in[0];
    const float* w_ih0  = (const float*)d_in[1];
    const float* w_ih12 = (const float*)d_in[2];
    const float* w_hh   = (const float*)d_in[3];
    const float* b_ih   = (const float*)d_in[4];
    const float* b_hh   = (const float*)d_in[5];
    const float* fc_w   = (const float*)d_in[6];
    const float* fc_b   = (const float*)d_in[7];
    float* out = (float*)d_out;

    const int threads = NSEQ * HDIM;   // 65536 -> 1024 waves -> 1/SIMD
    const int block = 256;
    gru3_fused<<<threads / block, block, 0, stream>>>(
        x, w_ih0, w_ih12, w_hh, b_ih, b_hh, fc_w, fc_b, out);
}

// Round 2
// 841.503 us; speedup vs baseline: 1.2456x; 1.2456x over previous
//
#include <hip/hip_runtime.h>

#define TSTEPS 1024
#define NSEQ 4096

typedef float v2f __attribute__((ext_vector_type(2)));

// sum across the two column-halves: v + (v from lane^16), within each
// 32-lane seq group. BitMode offset (xor<<10)|(or<<5)|and = 0x401F.
__device__ __forceinline__ float swz_add_xor16(float v) {
    float o = __int_as_float(
        __builtin_amdgcn_ds_swizzle(__float_as_int(v), 0x401F));
    return v + o;
}
__device__ __forceinline__ float bperm(int byte_addr, float v) {
    return __int_as_float(
        __builtin_amdgcn_ds_bpermute(byte_addr, __float_as_int(v)));
}
__device__ __forceinline__ float sigf(float v) {
    return __builtin_amdgcn_rcpf(1.0f + __expf(-v));  // ~1ulp, ok vs 6.3e-3
}
__device__ __forceinline__ float tanh_fast(float u) {
    // tanh(u) = 1 - 2/(exp(2u)+1); overflow -> rcp(inf)=0 -> 1.0, correct
    return 1.0f - 2.0f * __builtin_amdgcn_rcpf(__expf(2.0f * u) + 1.0f);
}

#define PKFMA(a, b, c) __builtin_elementwise_fma((a), (b), (c))

__global__ __launch_bounds__(256, 2) void gru3_fused2(
    const float* __restrict__ x,      // [4096,1024,1]
    const float* __restrict__ w_ih0,  // [48,1]
    const float* __restrict__ w_ih12, // [2,48,16]
    const float* __restrict__ w_hh,   // [3,48,16]
    const float* __restrict__ b_ih,   // [3,48]
    const float* __restrict__ b_hh,   // [3,48]
    const float* __restrict__ fc_w,   // [5,16]
    const float* __restrict__ fc_b,   // [5]
    float* __restrict__ out)          // [4096,5]
{
    const int tid = blockIdx.x * blockDim.x + threadIdx.x;
    const int seq = tid >> 5;                  // 32 lanes per sequence
    const int i = threadIdx.x & 15;            // hidden unit owned
    const int c = (threadIdx.x >> 4) & 1;      // column half: cols c*8..c*8+7

    // ---- per-lane weights: rows {i,16+i,32+i}, cols c*8..c*8+7, as f32 pairs
    v2f whh[3][3][4];  // [layer][gate r,z,n][pair]
    v2f wih[2][3][4];
#pragma unroll
    for (int l = 0; l < 3; ++l)
#pragma unroll
        for (int g = 0; g < 3; ++g)
#pragma unroll
            for (int m = 0; m < 4; ++m)
                whh[l][g][m] =
                    *(const v2f*)(w_hh + (l * 48 + g * 16 + i) * 16 + c * 8 + 2 * m);
#pragma unroll
    for (int l = 0; l < 2; ++l)
#pragma unroll
        for (int g = 0; g < 3; ++g)
#pragma unroll
            for (int m = 0; m < 4; ++m)
                wih[l][g][m] =
                    *(const v2f*)(w_ih12 + (l * 48 + g * 16 + i) * 16 + c * 8 + 2 * m);

    float br[3], bz[3], bnx[3], bnh[3];
#pragma unroll
    for (int l = 0; l < 3; ++l) {
        br[l]  = b_ih[l * 48 + i]      + b_hh[l * 48 + i];
        bz[l]  = b_ih[l * 48 + 16 + i] + b_hh[l * 48 + 16 + i];
        bnx[l] = b_ih[l * 48 + 32 + i];
        bnh[l] = b_hh[l * 48 + 32 + i];
    }
    const float wxr = w_ih0[i], wxz = w_ih0[16 + i], wxn = w_ih0[32 + i];

    // ---- bpermute byte addresses
    const int seqsel = (threadIdx.x & 32) * 4;              // seq-group base
    const int hbase = seqsel + ((threadIdx.x & 16) >> 1) * 4;  // + c*8 lanes
    int bca[8];
#pragma unroll
    for (int m = 0; m < 8; ++m) bca[m] = hbase + m * 4;

    // ---- state: h pairs for this lane's 8 columns + own h value
    v2f h0p[4], h1p[4], h2p[4];
#pragma unroll
    for (int m = 0; m < 4; ++m) {
        h0p[m] = (v2f){0.f, 0.f};
        h1p[m] = (v2f){0.f, 0.f};
        h2p[m] = (v2f){0.f, 0.f};
    }
    float h0o = 0.f, h1o = 0.f, h2o = 0.f;

    const float* xp = x + seq * TSTEPS;
    const int l5 = threadIdx.x & 31;
    float xv = xp[l5];  // 32 timesteps staged across the seq group

    for (int tb = 0; tb < 32; ++tb) {
        const int nxt = (tb < 31) ? (tb + 1) * 32 : 992;  // last: dummy in-bounds
        float xvn = xp[nxt + l5];
#pragma unroll 2
        for (int k = 0; k < 32; ++k) {
            const float xt = bperm(seqsel + 4 * k, xv);

            // ---- all three recurrent matvecs first (independent at step start)
            v2f a0r = whh[0][0][0] * h0p[0];
            v2f a0z = whh[0][1][0] * h0p[0];
            v2f a0n = whh[0][2][0] * h0p[0];
            v2f a1r = whh[1][0][0] * h1p[0];
            v2f a1z = whh[1][1][0] * h1p[0];
            v2f a1n = whh[1][2][0] * h1p[0];
            v2f a2r = whh[2][0][0] * h2p[0];
            v2f a2z = whh[2][1][0] * h2p[0];
            v2f a2n = whh[2][2][0] * h2p[0];
#pragma unroll
            for (int m = 1; m < 4; ++m) {
                a0r = PKFMA(whh[0][0][m], h0p[m], a0r);
                a0z = PKFMA(whh[0][1][m], h0p[m], a0z);
                a0n = PKFMA(whh[0][2][m], h0p[m], a0n);
                a1r = PKFMA(whh[1][0][m], h1p[m], a1r);
                a1z = PKFMA(whh[1][1][m], h1p[m], a1z);
                a1n = PKFMA(whh[1][2][m], h1p[m], a1n);
                a2r = PKFMA(whh[2][0][m], h2p[m], a2r);
                a2z = PKFMA(whh[2][1][m], h2p[m], a2z);
                a2n = PKFMA(whh[2][2][m], h2p[m], a2n);
            }

            // ---- layer 0 gates
            {
                float ar = swz_add_xor16(a0r.x + a0r.y) + br[0];
                float az = swz_add_xor16(a0z.x + a0z.y) + bz[0];
                float anh = swz_add_xor16(a0n.x + a0n.y) + bnh[0];
                ar = fmaf(wxr, xt, ar);
                az = fmaf(wxz, xt, az);
                float anx = fmaf(wxn, xt, bnx[0]);
                float r = sigf(ar), z = sigf(az);
                float n = tanh_fast(fmaf(r, anh, anx));
                h0o = n + z * (h0o - n);
            }
#pragma unroll
            for (int m = 0; m < 4; ++m) {
                h0p[m].x = bperm(bca[2 * m], h0o);
                h0p[m].y = bperm(bca[2 * m + 1], h0o);
            }

            // ---- layer 1: add input-side (h0p fresh), then gates
            {
                v2f a1x = wih[0][2][0] * h0p[0];
                a1r = PKFMA(wih[0][0][0], h0p[0], a1r);
                a1z = PKFMA(wih[0][1][0], h0p[0], a1z);
#pragma unroll
                for (int m = 1; m < 4; ++m) {
                    a1r = PKFMA(wih[0][0][m], h0p[m], a1r);
                    a1z = PKFMA(wih[0][1][m], h0p[m], a1z);
                    a1x = PKFMA(wih[0][2][m], h0p[m], a1x);
                }
                float ar = swz_add_xor16(a1r.x + a1r.y) + br[1];
                float az = swz_add_xor16(a1z.x + a1z.y) + bz[1];
                float anh = swz_add_xor16(a1n.x + a1n.y) + bnh[1];
                float anx = swz_add_xor16(a1x.x + a1x.y) + bnx[1];
                float r = sigf(ar), z = sigf(az);
                float n = tanh_fast(fmaf(r, anh, anx));
                h1o = n + z * (h1o - n);
            }
#pragma unroll
            for (int m = 0; m < 4; ++m) {
                h1p[m].x = bperm(bca[2 * m], h1o);
                h1p[m].y = bperm(bca[2 * m + 1], h1o);
            }

            // ---- layer 2
            {
                v2f a2x = wih[1][2][0] * h1p[0];
                a2r = PKFMA(wih[1][0][0], h1p[0], a2r);
                a2z = PKFMA(wih[1][1][0], h1p[0], a2z);
#pragma unroll
                for (int m = 1; m < 4; ++m) {
                    a2r = PKFMA(wih[1][0][m], h1p[m], a2r);
                    a2z = PKFMA(wih[1][1][m], h1p[m], a2z);
                    a2x = PKFMA(wih[1][2][m], h1p[m], a2x);
                }
                float ar = swz_add_xor16(a2r.x + a2r.y) + br[2];
                float az = swz_add_xor16(a2z.x + a2z.y) + bz[2];
                float anh = swz_add_xor16(a2n.x + a2n.y) + bnh[2];
                float anx = swz_add_xor16(a2x.x + a2x.y) + bnx[2];
                float r = sigf(ar), z = sigf(az);
                float n = tanh_fast(fmaf(r, anh, anx));
                h2o = n + z * (h2o - n);
            }
#pragma unroll
            for (int m = 0; m < 4; ++m) {
                h2p[m].x = bperm(bca[2 * m], h2o);
                h2p[m].y = bperm(bca[2 * m + 1], h2o);
            }
        }
        xv = xvn;
    }

    // ---- head: full-wave bpermute (no divergence), then guarded store
    float hhi[8];
#pragma unroll
    for (int m = 0; m < 8; ++m) hhi[m] = bperm(seqsel + (8 + m) * 4, h2o);

    if ((threadIdx.x & 31) < 5) {  // half0 lanes, unit i < 5
        float h[16];
#pragma unroll
        for (int m = 0; m < 4; ++m) {  // c==0 here: h2p = h[0..7]
            h[2 * m] = h2p[m].x;
            h[2 * m + 1] = h2p[m].y;
        }
#pragma unroll
        for (int m = 0; m < 8; ++m) h[8 + m] = hhi[m];
        float acc = fc_b[i];
#pragma unroll
        for (int j = 0; j < 16; ++j) acc = fmaf(fc_w[i * 16 + j], h[j], acc);
        out[seq * 5 + i] = acc;
    }
}

extern "C" void kernel_launch(void* const* d_in, const int* in_sizes, int n_in,
                              void* d_out, int out_size, void* d_ws, size_t ws_size,
                              hipStream_t stream) {
    const float* x      = (const float*)d_in[0];
    const float* w_ih0  = (const float*)d_in[1];
    const float* w_ih12 = (const float*)d_in[2];
    const float* w_hh   = (const float*)d_in[3];
    const float* b_ih   = (const float*)d_in[4];
    const float* b_hh   = (const float*)d_in[5];
    const float* fc_w   = (const float*)d_in[6];
    const float* fc_b   = (const float*)d_in[7];
    float* out = (float*)d_out;

    const int threads = NSEQ * 32;  // 131072 -> 2048 waves -> 2/SIMD
    gru3_fused2<<<threads / 256, 256, 0, stream>>>(
        x, w_ih0, w_ih12, w_hh, b_ih, b_hh, fc_w, fc_b, out);
}

// Round 3
// 829.279 us; speedup vs baseline: 1.2640x; 1.0147x over previous
//
#include <hip/hip_runtime.h>

#define TSTEPS 1024
#define NSEQ 4096
#define L2E 1.4426950408889634f

typedef float v2f __attribute__((ext_vector_type(2)));

// sum across the two column-halves within each 32-lane seq group.
// BitMode offset (xor<<10)|(or<<5)|and = 0x401F -> src = lane ^ 16.
__device__ __forceinline__ float swz_add_xor16(float v) {
    float o = __int_as_float(
        __builtin_amdgcn_ds_swizzle(__float_as_int(v), 0x401F));
    return v + o;
}
__device__ __forceinline__ float bperm(int byte_addr, float v) {
    return __int_as_float(
        __builtin_amdgcn_ds_bpermute(byte_addr, __float_as_int(v)));
}
__device__ __forceinline__ float rcpf_(float v) {
    return __builtin_amdgcn_rcpf(v);
}
__device__ __forceinline__ float ex2(float v) {
    return __builtin_amdgcn_exp2f(v);
}
#define PKFMA(a, b, c) __builtin_elementwise_fma((a), (b), (c))
// Pin a value into a VGPR: asm-defined values cannot be rematerialized as
// (invariant) loads by the register allocator -> weights stay resident.
#define PIN(v) asm("" : "+v"(v))

// One diagonal iteration: L0 at t=T0, L1 at T0-1, L2 at T0-2 (independent).
// All matvec partials consume the OLD h*p broadcasts; broadcasts at the end.
#define STEP(DO0, DO1, DO2, T0)                                               \
  do {                                                                        \
    float xt = 0.f;                                                           \
    if (DO0) xt = xs[xofs + (T0)];                                            \
    v2f a0r = {0.f, 0.f}, a0z = a0r, a0n = a0r;                               \
    v2f a1r = a0r, a1z = a0r, a1nh = a0r, a1nx = a0r;                         \
    v2f a2r = a0r, a2z = a0r, a2nh = a0r, a2nx = a0r;                         \
    if (DO0) {                                                                \
      a0r = whh_[0][0][0] * h0p[0];                                           \
      a0z = whh_[0][1][0] * h0p[0];                                           \
      a0n = whh_[0][2][0] * h0p[0];                                           \
      _Pragma("unroll") for (int m = 1; m < 4; ++m) {                         \
        a0r = PKFMA(whh_[0][0][m], h0p[m], a0r);                              \
        a0z = PKFMA(whh_[0][1][m], h0p[m], a0z);                              \
        a0n = PKFMA(whh_[0][2][m], h0p[m], a0n);                              \
      }                                                                       \
    }                                                                         \
    if (DO1) {                                                                \
      a1r = whh_[1][0][0] * h1p[0];                                           \
      a1z = whh_[1][1][0] * h1p[0];                                           \
      a1nh = whh_[1][2][0] * h1p[0];                                          \
      a1nx = wih_[0][2][0] * h0p[0];                                          \
      a1r = PKFMA(wih_[0][0][0], h0p[0], a1r);                                \
      a1z = PKFMA(wih_[0][1][0], h0p[0], a1z);                                \
      _Pragma("unroll") for (int m = 1; m < 4; ++m) {                         \
        a1r = PKFMA(whh_[1][0][m], h1p[m], a1r);                              \
        a1z = PKFMA(whh_[1][1][m], h1p[m], a1z);                              \
        a1nh = PKFMA(whh_[1][2][m], h1p[m], a1nh);                            \
        a1r = PKFMA(wih_[0][0][m], h0p[m], a1r);                              \
        a1z = PKFMA(wih_[0][1][m], h0p[m], a1z);                              \
        a1nx = PKFMA(wih_[0][2][m], h0p[m], a1nx);                            \
      }                                                                       \
    }                                                                         \
    if (DO2) {                                                                \
      a2r = whh_[2][0][0] * h2p[0];                                           \
      a2z = whh_[2][1][0] * h2p[0];                                           \
      a2nh = whh_[2][2][0] * h2p[0];                                          \
      a2nx = wih_[1][2][0] * h1p[0];                                          \
      a2r = PKFMA(wih_[1][0][0], h1p[0], a2r);                                \
      a2z = PKFMA(wih_[1][1][0], h1p[0], a2z);                                \
      _Pragma("unroll") for (int m = 1; m < 4; ++m) {                         \
        a2r = PKFMA(whh_[2][0][m], h2p[m], a2r);                              \
        a2z = PKFMA(whh_[2][1][m], h2p[m], a2z);                              \
        a2nh = PKFMA(whh_[2][2][m], h2p[m], a2nh);                            \
        a2r = PKFMA(wih_[1][0][m], h1p[m], a2r);                              \
        a2z = PKFMA(wih_[1][1][m], h1p[m], a2z);                              \
        a2nx = PKFMA(wih_[1][2][m], h1p[m], a2nx);                            \
      }                                                                       \
    }                                                                         \
    if (DO0) {                                                                \
      float sr = fmaf(wxr, xt, swz_add_xor16(a0r.x + a0r.y));                 \
      float r = rcpf_(1.f + ex2(fmaf(sr, -L2E, nbr[0])));                     \
      float sz = fmaf(wxz, xt, swz_add_xor16(a0z.x + a0z.y));                 \
      float z = rcpf_(1.f + ex2(fmaf(sz, -L2E, nbz[0])));                     \
      float ah = swz_add_xor16(a0n.x + a0n.y) + bnh_[0];                      \
      float ax = fmaf(wxn, xt, bnx_[0]);                                      \
      float u = fmaf(r, ah, ax);                                              \
      float n = fmaf(-2.f, rcpf_(ex2(u * (2.f * L2E)) + 1.f), 1.f);           \
      h0o = fmaf(z, h0o - n, n);                                              \
    }                                                                         \
    if (DO1) {                                                                \
      float sr = swz_add_xor16(a1r.x + a1r.y);                                \
      float r = rcpf_(1.f + ex2(fmaf(sr, -L2E, nbr[1])));                     \
      float sz = swz_add_xor16(a1z.x + a1z.y);                                \
      float z = rcpf_(1.f + ex2(fmaf(sz, -L2E, nbz[1])));                     \
      float ah = swz_add_xor16(a1nh.x + a1nh.y) + bnh_[1];                    \
      float ax = swz_add_xor16(a1nx.x + a1nx.y) + bnx_[1];                    \
      float u = fmaf(r, ah, ax);                                              \
      float n = fmaf(-2.f, rcpf_(ex2(u * (2.f * L2E)) + 1.f), 1.f);           \
      h1o = fmaf(z, h1o - n, n);                                              \
    }                                                                         \
    if (DO2) {                                                                \
      float sr = swz_add_xor16(a2r.x + a2r.y);                                \
      float r = rcpf_(1.f + ex2(fmaf(sr, -L2E, nbr[2])));                     \
      float sz = swz_add_xor16(a2z.x + a2z.y);                                \
      float z = rcpf_(1.f + ex2(fmaf(sz, -L2E, nbz[2])));                     \
      float ah = swz_add_xor16(a2nh.x + a2nh.y) + bnh_[2];                    \
      float ax = swz_add_xor16(a2nx.x + a2nx.y) + bnx_[2];                    \
      float u = fmaf(r, ah, ax);                                              \
      float n = fmaf(-2.f, rcpf_(ex2(u * (2.f * L2E)) + 1.f), 1.f);           \
      h2o = fmaf(z, h2o - n, n);                                              \
    }                                                                         \
    if (DO0) {                                                                \
      _Pragma("unroll") for (int m = 0; m < 4; ++m) {                         \
        h0p[m].x = bperm(bca[2 * m], h0o);                                    \
        h0p[m].y = bperm(bca[2 * m + 1], h0o);                                \
      }                                                                       \
    }                                                                         \
    if (DO1) {                                                                \
      _Pragma("unroll") for (int m = 0; m < 4; ++m) {                         \
        h1p[m].x = bperm(bca[2 * m], h1o);                                    \
        h1p[m].y = bperm(bca[2 * m + 1], h1o);                                \
      }                                                                       \
    }                                                                         \
    if (DO2) {                                                                \
      _Pragma("unroll") for (int m = 0; m < 4; ++m) {                         \
        h2p[m].x = bperm(bca[2 * m], h2o);                                    \
        h2p[m].y = bperm(bca[2 * m + 1], h2o);                                \
      }                                                                       \
    }                                                                         \
  } while (0)

__global__ __launch_bounds__(256, 2) void gru3_fused3(
    const float* __restrict__ x,      // [4096,1024,1]
    const float* __restrict__ w_ih0,  // [48,1]
    const float* __restrict__ w_ih12, // [2,48,16]
    const float* __restrict__ w_hh,   // [3,48,16]
    const float* __restrict__ b_ih,   // [3,48]
    const float* __restrict__ b_hh,   // [3,48]
    const float* __restrict__ fc_w,   // [5,16]
    const float* __restrict__ fc_b,   // [5]
    float* __restrict__ out)          // [4096,5]
{
    __shared__ float xs[8 * TSTEPS];  // 32 KB: x rows for this block's 8 seqs

    const int tid = blockIdx.x * blockDim.x + threadIdx.x;
    const int seq = tid >> 5;              // 32 lanes per sequence
    const int i = threadIdx.x & 15;        // hidden unit owned
    const int c = (threadIdx.x >> 4) & 1;  // column half: cols c*8..c*8+7
    const int grp = threadIdx.x >> 5;      // seq slot within block (0..7)
    const int xofs = grp * TSTEPS;

    // ---- stage x into LDS (coalesced float4, once)
    {
        const float4* xg = (const float4*)(x + (size_t)blockIdx.x * 8 * TSTEPS);
        float4* xs4 = (float4*)xs;
#pragma unroll
        for (int j = 0; j < 8; ++j)
            xs4[threadIdx.x + 256 * j] = xg[threadIdx.x + 256 * j];
    }

    // ---- per-lane weights, pinned into VGPRs (PIN defeats load-remat)
    v2f whh_[3][3][4];  // [layer][gate r,z,n][col pair]
    v2f wih_[2][3][4];
#pragma unroll
    for (int l = 0; l < 3; ++l)
#pragma unroll
        for (int g = 0; g < 3; ++g)
#pragma unroll
            for (int m = 0; m < 4; ++m) {
                whh_[l][g][m] =
                    *(const v2f*)(w_hh + (l * 48 + g * 16 + i) * 16 + c * 8 + 2 * m);
                PIN(whh_[l][g][m]);
            }
#pragma unroll
    for (int l = 0; l < 2; ++l)
#pragma unroll
        for (int g = 0; g < 3; ++g)
#pragma unroll
            for (int m = 0; m < 4; ++m) {
                wih_[l][g][m] =
                    *(const v2f*)(w_ih12 + (l * 48 + g * 16 + i) * 16 + c * 8 + 2 * m);
                PIN(wih_[l][g][m]);
            }

    // ---- biases folded for exp2-based gates
    float nbr[3], nbz[3], bnh_[3], bnx_[3];
#pragma unroll
    for (int l = 0; l < 3; ++l) {
        nbr[l] = -(b_ih[l * 48 + i] + b_hh[l * 48 + i]) * L2E;
        nbz[l] = -(b_ih[l * 48 + 16 + i] + b_hh[l * 48 + 16 + i]) * L2E;
        bnh_[l] = b_hh[l * 48 + 32 + i];
        bnx_[l] = b_ih[l * 48 + 32 + i];
        PIN(nbr[l]); PIN(nbz[l]); PIN(bnh_[l]); PIN(bnx_[l]);
    }
    float wxr = w_ih0[i], wxz = w_ih0[16 + i], wxn = w_ih0[32 + i];
    PIN(wxr); PIN(wxz); PIN(wxn);

    // ---- bpermute byte addresses (own half's 8 unit-owner lanes)
    const int seqsel = (threadIdx.x & 32) * 4;
    const int hbase = seqsel + ((threadIdx.x & 16) >> 1) * 4;  // + c*8 lanes
    int bca[8];
#pragma unroll
    for (int m = 0; m < 8; ++m) bca[m] = hbase + m * 4;

    // ---- state (diagonal schedule): h0p=h0(t0-1), h1p=h1(t0-2), h2p=h2(t0-3)
    v2f h0p[4], h1p[4], h2p[4];
#pragma unroll
    for (int m = 0; m < 4; ++m) {
        h0p[m] = (v2f){0.f, 0.f};
        h1p[m] = (v2f){0.f, 0.f};
        h2p[m] = (v2f){0.f, 0.f};
    }
    float h0o = 0.f, h1o = 0.f, h2o = 0.f;

    __syncthreads();  // xs ready

    // ---- prologue, steady-state, epilogue
    STEP(1, 0, 0, 0);
    STEP(1, 1, 0, 1);
#pragma unroll 2
    for (int t0 = 2; t0 < TSTEPS; ++t0) STEP(1, 1, 1, t0);
    STEP(0, 1, 1, TSTEPS);
    STEP(0, 0, 1, TSTEPS + 1);

    // ---- head on h2(1023): lanes 0-4 of each group (c==0 -> h2p = cols 0..7)
    float hhi[8];
#pragma unroll
    for (int m = 0; m < 8; ++m) hhi[m] = bperm(seqsel + (8 + m) * 4, h2o);

    if ((threadIdx.x & 31) < 5) {
        float h[16];
#pragma unroll
        for (int m = 0; m < 4; ++m) {
            h[2 * m] = h2p[m].x;
            h[2 * m + 1] = h2p[m].y;
        }
#pragma unroll
        for (int m = 0; m < 8; ++m) h[8 + m] = hhi[m];
        float acc = fc_b[i];
#pragma unroll
        for (int j = 0; j < 16; ++j) acc = fmaf(fc_w[i * 16 + j], h[j], acc);
        out[seq * 5 + i] = acc;
    }
}

extern "C" void kernel_launch(void* const* d_in, const int* in_sizes, int n_in,
                              void* d_out, int out_size, void* d_ws, size_t ws_size,
                              hipStream_t stream) {
    const float* x      = (const float*)d_in[0];
    const float* w_ih0  = (const float*)d_in[1];
    const float* w_ih12 = (const float*)d_in[2];
    const float* w_hh   = (const float*)d_in[3];
    const float* b_ih   = (const float*)d_in[4];
    const float* b_hh   = (const float*)d_in[5];
    const float* fc_w   = (const float*)d_in[6];
    const float* fc_b   = (const float*)d_in[7];
    float* out = (float*)d_out;

    const int threads = NSEQ * 32;  // 131072 -> 2048 waves -> 2/SIMD
    gru3_fused3<<<threads / 256, 256, 0, stream>>>(
        x, w_ih0, w_ih12, w_hh, b_ih, b_hh, fc_w, fc_b, out);
}

// Round 4
// 685.418 us; speedup vs baseline: 1.5293x; 1.2099x over previous
//
#include <hip/hip_runtime.h>
#include <stdint.h>

#define TSTEPS 1024
#define NSEQ 4096
#define L2E 1.4426950408889634f
#define XPITCH (TSTEPS + 8)  // pad: x broadcast reads from 8 groups hit 8 banks

typedef float v2f __attribute__((ext_vector_type(2)));

// sum across the two column-halves within each 32-lane seq group (lane^16).
__device__ __forceinline__ float swz_add_xor16(float v) {
    float o = __int_as_float(
        __builtin_amdgcn_ds_swizzle(__float_as_int(v), 0x401F));
    return v + o;
}
__device__ __forceinline__ float rcpf_(float v) {
    return __builtin_amdgcn_rcpf(v);
}
__device__ __forceinline__ float ex2(float v) {
    return __builtin_amdgcn_exp2f(v);
}
#define PKFMA(a, b, c) __builtin_elementwise_fma((a), (b), (c))

// Opaque weight loads: the VALUE is asm-produced, so the register allocator
// cannot rematerialize it as a (loop-invariant) load — it must stay resident.
// waitcnt inside the same asm so the result is architecturally ready.
__device__ __forceinline__ v2f ldg2(const float* p) {
    v2f r;
    uint64_t a = (uint64_t)p;
    asm volatile("global_load_dwordx2 %0, %1, off\n\ts_waitcnt vmcnt(0)"
                 : "=v"(r)
                 : "v"(a));
    return r;
}
__device__ __forceinline__ float ldg1(const float* p) {
    float r;
    uint64_t a = (uint64_t)p;
    asm volatile("global_load_dword %0, %1, off\n\ts_waitcnt vmcnt(0)"
                 : "=v"(r)
                 : "v"(a));
    return r;
}

// Diagonal iteration: L0 at t=T0, L1 at T0-1, L2 at T0-2 (independent).
// h replication via LDS: write own h (both halves, same value), read back
// this lane's 4 column pairs. Wave-internal DS ops: in-order, no barrier.
#define STEP(F0, F1, F2, T0)                                                  \
  do {                                                                        \
    float xt = 0.f;                                                           \
    if (F0) xt = xs[xofs + (T0)];                                             \
    v2f a0r = {0.f, 0.f}, a0z = a0r, a0n = a0r;                               \
    v2f a1r = a0r, a1z = a0r, a1nh = a0r, a1nx = a0r;                         \
    v2f a2r = a0r, a2z = a0r, a2nh = a0r, a2nx = a0r;                         \
    if (F0) {                                                                 \
      a0r = whh_[0][0][0] * h0p[0];                                           \
      a0z = whh_[0][1][0] * h0p[0];                                           \
      a0n = whh_[0][2][0] * h0p[0];                                           \
      _Pragma("unroll") for (int m = 1; m < 4; ++m) {                         \
        a0r = PKFMA(whh_[0][0][m], h0p[m], a0r);                              \
        a0z = PKFMA(whh_[0][1][m], h0p[m], a0z);                              \
        a0n = PKFMA(whh_[0][2][m], h0p[m], a0n);                              \
      }                                                                       \
    }                                                                         \
    if (F1) {                                                                 \
      a1r = whh_[1][0][0] * h1p[0];                                           \
      a1z = whh_[1][1][0] * h1p[0];                                           \
      a1nh = whh_[1][2][0] * h1p[0];                                          \
      a1nx = wih_[0][2][0] * h0p[0];                                          \
      a1r = PKFMA(wih_[0][0][0], h0p[0], a1r);                                \
      a1z = PKFMA(wih_[0][1][0], h0p[0], a1z);                                \
      _Pragma("unroll") for (int m = 1; m < 4; ++m) {                         \
        a1r = PKFMA(whh_[1][0][m], h1p[m], a1r);                              \
        a1z = PKFMA(whh_[1][1][m], h1p[m], a1z);                              \
        a1nh = PKFMA(whh_[1][2][m], h1p[m], a1nh);                            \
        a1r = PKFMA(wih_[0][0][m], h0p[m], a1r);                              \
        a1z = PKFMA(wih_[0][1][m], h0p[m], a1z);                              \
        a1nx = PKFMA(wih_[0][2][m], h0p[m], a1nx);                            \
      }                                                                       \
    }                                                                         \
    if (F2) {                                                                 \
      a2r = whh_[2][0][0] * h2p[0];                                           \
      a2z = whh_[2][1][0] * h2p[0];                                           \
      a2nh = whh_[2][2][0] * h2p[0];                                          \
      a2nx = wih_[1][2][0] * h1p[0];                                          \
      a2r = PKFMA(wih_[1][0][0], h1p[0], a2r);                                \
      a2z = PKFMA(wih_[1][1][0], h1p[0], a2z);                                \
      _Pragma("unroll") for (int m = 1; m < 4; ++m) {                         \
        a2r = PKFMA(whh_[2][0][m], h2p[m], a2r);                              \
        a2z = PKFMA(whh_[2][1][m], h2p[m], a2z);                              \
        a2nh = PKFMA(whh_[2][2][m], h2p[m], a2nh);                            \
        a2r = PKFMA(wih_[1][0][m], h1p[m], a2r);                              \
        a2z = PKFMA(wih_[1][1][m], h1p[m], a2z);                              \
        a2nx = PKFMA(wih_[1][2][m], h1p[m], a2nx);                            \
      }                                                                       \
    }                                                                         \
    if (F0) {                                                                 \
      float sr = fmaf(wxr, xt, swz_add_xor16(a0r.x + a0r.y));                 \
      float r = rcpf_(1.f + ex2(fmaf(sr, -L2E, nbr[0])));                     \
      float sz = fmaf(wxz, xt, swz_add_xor16(a0z.x + a0z.y));                 \
      float z = rcpf_(1.f + ex2(fmaf(sz, -L2E, nbz[0])));                     \
      float ah = swz_add_xor16(a0n.x + a0n.y) + bnh_[0];                      \
      float ax = fmaf(wxn, xt, bnx_[0]);                                      \
      float u = fmaf(r, ah, ax);                                              \
      float n = fmaf(-2.f, rcpf_(ex2(u * (2.f * L2E)) + 1.f), 1.f);           \
      h0o = fmaf(z, h0o - n, n);                                              \
      hr[0 * 16 + i] = h0o;                                                   \
      _Pragma("unroll") for (int m = 0; m < 4; ++m)                           \
          h0p[m] = *(const v2f*)(hr + 0 * 16 + c8 + 2 * m);                   \
    }                                                                         \
    if (F1) {                                                                 \
      float sr = swz_add_xor16(a1r.x + a1r.y);                                \
      float r = rcpf_(1.f + ex2(fmaf(sr, -L2E, nbr[1])));                     \
      float sz = swz_add_xor16(a1z.x + a1z.y);                                \
      float z = rcpf_(1.f + ex2(fmaf(sz, -L2E, nbz[1])));                     \
      float ah = swz_add_xor16(a1nh.x + a1nh.y) + bnh_[1];                    \
      float ax = swz_add_xor16(a1nx.x + a1nx.y) + bnx_[1];                    \
      float u = fmaf(r, ah, ax);                                              \
      float n = fmaf(-2.f, rcpf_(ex2(u * (2.f * L2E)) + 1.f), 1.f);           \
      h1o = fmaf(z, h1o - n, n);                                              \
      hr[1 * 16 + i] = h1o;                                                   \
      _Pragma("unroll") for (int m = 0; m < 4; ++m)                           \
          h1p[m] = *(const v2f*)(hr + 1 * 16 + c8 + 2 * m);                   \
    }                                                                         \
    if (F2) {                                                                 \
      float sr = swz_add_xor16(a2r.x + a2r.y);                                \
      float r = rcpf_(1.f + ex2(fmaf(sr, -L2E, nbr[2])));                     \
      float sz = swz_add_xor16(a2z.x + a2z.y);                                \
      float z = rcpf_(1.f + ex2(fmaf(sz, -L2E, nbz[2])));                     \
      float ah = swz_add_xor16(a2nh.x + a2nh.y) + bnh_[2];                    \
      float ax = swz_add_xor16(a2nx.x + a2nx.y) + bnx_[2];                    \
      float u = fmaf(r, ah, ax);                                              \
      float n = fmaf(-2.f, rcpf_(ex2(u * (2.f * L2E)) + 1.f), 1.f);           \
      h2o = fmaf(z, h2o - n, n);                                              \
      hr[2 * 16 + i] = h2o;                                                   \
      _Pragma("unroll") for (int m = 0; m < 4; ++m)                           \
          h2p[m] = *(const v2f*)(hr + 2 * 16 + c8 + 2 * m);                   \
    }                                                                         \
  } while (0)

__global__ __launch_bounds__(256, 2) void gru3_fused4(
    const float* __restrict__ x,      // [4096,1024,1]
    const float* __restrict__ w_ih0,  // [48,1]
    const float* __restrict__ w_ih12, // [2,48,16]
    const float* __restrict__ w_hh,   // [3,48,16]
    const float* __restrict__ b_ih,   // [3,48]
    const float* __restrict__ b_hh,   // [3,48]
    const float* __restrict__ fc_w,   // [5,16]
    const float* __restrict__ fc_b,   // [5]
    float* __restrict__ out)          // [4096,5]
{
    __shared__ float xs[8 * XPITCH];   // 33 KB padded x rows
    __shared__ float hrep[8][3][16];   // per-group replicated hidden vectors

    const int tid = blockIdx.x * blockDim.x + threadIdx.x;
    const int seq = tid >> 5;              // 32 lanes per sequence
    const int i = threadIdx.x & 15;        // hidden unit owned
    const int c8 = (threadIdx.x >> 1) & 8; // column-half offset (c*8)
    const int grp = threadIdx.x >> 5;      // seq slot in block (0..7)
    const int xofs = grp * XPITCH;
    float* hr = &hrep[grp][0][0];

    // ---- stage x into LDS (coalesced float4, once)
    {
        const float4* xg4 = (const float4*)(x + (size_t)blockIdx.x * 8 * TSTEPS);
#pragma unroll
        for (int j = 0; j < 8; ++j) {
            int idx = threadIdx.x + 256 * j;
            float4 v = xg4[idx];
            int sl = idx >> 8;
            int of = (idx & 255) * 4;
            *(float4*)&xs[sl * XPITCH + of] = v;
        }
    }

    // ---- weights: asm-opaque loads -> guaranteed VGPR-resident
    v2f whh_[3][3][4];  // [layer][gate r,z,n][col pair]
    v2f wih_[2][3][4];
#pragma unroll
    for (int l = 0; l < 3; ++l)
#pragma unroll
        for (int g = 0; g < 3; ++g)
#pragma unroll
            for (int m = 0; m < 4; ++m)
                whh_[l][g][m] =
                    ldg2(w_hh + (l * 48 + g * 16 + i) * 16 + c8 + 2 * m);
#pragma unroll
    for (int l = 0; l < 2; ++l)
#pragma unroll
        for (int g = 0; g < 3; ++g)
#pragma unroll
            for (int m = 0; m < 4; ++m)
                wih_[l][g][m] =
                    ldg2(w_ih12 + (l * 48 + g * 16 + i) * 16 + c8 + 2 * m);

    float nbr[3], nbz[3], bnh_[3], bnx_[3];
#pragma unroll
    for (int l = 0; l < 3; ++l) {
        nbr[l] = -(ldg1(b_ih + l * 48 + i) + ldg1(b_hh + l * 48 + i)) * L2E;
        nbz[l] = -(ldg1(b_ih + l * 48 + 16 + i) + ldg1(b_hh + l * 48 + 16 + i)) * L2E;
        bnh_[l] = ldg1(b_hh + l * 48 + 32 + i);
        bnx_[l] = ldg1(b_ih + l * 48 + 32 + i);
    }
    const float wxr = ldg1(w_ih0 + i);
    const float wxz = ldg1(w_ih0 + 16 + i);
    const float wxn = ldg1(w_ih0 + 32 + i);

    // ---- state (diagonal): h0p=h0(t0-1), h1p=h1(t0-2), h2p=h2(t0-3)
    v2f h0p[4], h1p[4], h2p[4];
#pragma unroll
    for (int m = 0; m < 4; ++m) {
        h0p[m] = (v2f){0.f, 0.f};
        h1p[m] = (v2f){0.f, 0.f};
        h2p[m] = (v2f){0.f, 0.f};
    }
    float h0o = 0.f, h1o = 0.f, h2o = 0.f;

    __syncthreads();  // xs ready (staging is cross-group)

    STEP(1, 0, 0, 0);
    STEP(1, 1, 0, 1);
    for (int t0 = 2; t0 < TSTEPS; ++t0) STEP(1, 1, 1, t0);
    STEP(0, 1, 1, TSTEPS);
    STEP(0, 0, 1, TSTEPS + 1);

    // ---- head on h2(1023): full vector from LDS replica
    v2f hf[8];
#pragma unroll
    for (int m = 0; m < 8; ++m) hf[m] = *(const v2f*)(hr + 2 * 16 + 2 * m);

    if ((threadIdx.x & 31) < 5) {
        float acc = fc_b[i];
#pragma unroll
        for (int m = 0; m < 8; ++m) {
            acc = fmaf(fc_w[i * 16 + 2 * m], hf[m].x, acc);
            acc = fmaf(fc_w[i * 16 + 2 * m + 1], hf[m].y, acc);
        }
        out[seq * 5 + i] = acc;
    }
}

extern "C" void kernel_launch(void* const* d_in, const int* in_sizes, int n_in,
                              void* d_out, int out_size, void* d_ws, size_t ws_size,
                              hipStream_t stream) {
    const float* x      = (const float*)d_in[0];
    const float* w_ih0  = (const float*)d_in[1];
    const float* w_ih12 = (const float*)d_in[2];
    const float* w_hh   = (const float*)d_in[3];
    const float* b_ih   = (const float*)d_in[4];
    const float* b_hh   = (const float*)d_in[5];
    const float* fc_w   = (const float*)d_in[6];
    const float* fc_b   = (const float*)d_in[7];
    float* out = (float*)d_out;

    const int threads = NSEQ * 32;  // 131072 -> 2048 waves -> 2/SIMD exactly
    gru3_fused4<<<threads / 256, 256, 0, stream>>>(
        x, w_ih0, w_ih12, w_hh, b_ih, b_hh, fc_w, fc_b, out);
}